// Round 9
// baseline (229.873 us; speedup 1.0000x reference)
//
#include <hip/hip_runtime.h>
#include <hip/hip_bf16.h>

typedef __attribute__((ext_vector_type(8))) short short8v;
typedef __attribute__((ext_vector_type(4))) float f32x4;

#define B_ 2
#define NTOK 4096
#define DMODEL 1024
#define HEADS_ 16
#define DH 64
#define SEG_ 512
#define PMEM 16
#define ROWS 8192      // B_*NTOK
#define QKVC 3072

// ---------------- RMSNorm -> bf16 ----------------
__global__ __launch_bounds__(256) void rmsnorm_bf16(const float* __restrict__ seq,
                                                    const float* __restrict__ g,
                                                    __hip_bfloat16* __restrict__ x) {
    int row = blockIdx.x;
    const float4* in = (const float4*)(seq + (size_t)row * DMODEL);
    int tid = threadIdx.x;
    float4 v = in[tid];
    float ss = v.x*v.x + v.y*v.y + v.z*v.z + v.w*v.w;
    #pragma unroll
    for (int off = 32; off >= 1; off >>= 1) ss += __shfl_xor(ss, off, 64);
    __shared__ float red[4];
    if ((tid & 63) == 0) red[tid >> 6] = ss;
    __syncthreads();
    float tot = red[0] + red[1] + red[2] + red[3];
    float scale = rsqrtf(tot * (1.0f/(float)DMODEL) + 1.1920929e-7f);
    float4 gv = ((const float4*)g)[tid];
    union { ushort4 u; __hip_bfloat16 h[4]; } pk;
    pk.h[0] = __float2bfloat16(v.x*scale*gv.x);
    pk.h[1] = __float2bfloat16(v.y*scale*gv.y);
    pk.h[2] = __float2bfloat16(v.z*scale*gv.z);
    pk.h[3] = __float2bfloat16(v.w*scale*gv.w);
    ((ushort4*)(x + (size_t)row * DMODEL))[tid] = pk.u;
}

// ---------------- transpose + convert: W[K,N] f32 -> Wt[N,K] bf16 ----------
__global__ __launch_bounds__(256) void transpose_bf16(const float* __restrict__ W,
                                                      __hip_bfloat16* __restrict__ Wt,
                                                      int K, int N) {
    __shared__ float t[32][33];
    int n0 = blockIdx.x * 32, k0 = blockIdx.y * 32;
    int c = threadIdx.x & 31, r = threadIdx.x >> 5;
    #pragma unroll
    for (int rr = 0; rr < 32; rr += 8)
        t[rr + r][c] = W[(size_t)(k0 + rr + r)*N + n0 + c];
    __syncthreads();
    #pragma unroll
    for (int rr = 0; rr < 32; rr += 8)
        Wt[(size_t)(n0 + rr + r)*K + k0 + c] = __float2bfloat16(t[c][rr + r]);
}

// ---------------- RoPE cos/sin table; pm f32 -> bf16 -----------------------
__global__ __launch_bounds__(256) void rope_table(float* __restrict__ tab) {
    int idx = blockIdx.x*256 + threadIdx.x;     // NTOK*32 threads
    int n = idx >> 5, p = idx & 31;
    float inv = powf(10000.f, -(float)p * (1.f/32.f));
    float a = (float)n * inv;
    float sn, cs;
    sincosf(a, &sn, &cs);
    tab[(size_t)n*64 + 2*p]     = cs;
    tab[(size_t)n*64 + 2*p + 1] = sn;
}

__global__ __launch_bounds__(256) void pm_bf16(const float* __restrict__ pm,
                                               __hip_bfloat16* __restrict__ pmb) {
    int idx = blockIdx.x*256 + threadIdx.x;     // 2*16*16*64 = 32768
    pmb[idx] = __float2bfloat16(pm[idx]);
}

__device__ __forceinline__ void gldl(const __hip_bfloat16* g, char* l) {
    __builtin_amdgcn_global_load_lds((const __attribute__((address_space(1))) void*)g,
                                     (__attribute__((address_space(3))) void*)l, 16, 0, 0);
}

// ---------------- 256x256 8-phase bf16 GEMM + fused RoPE (QKV) -------------
// Schedule fix vs round 7: stage for tile t+2 issues during tile t's PHASE 4
// (all reads of that buffer proven complete by the phase-3 exit barrier), so
// each 8-load burst has ~5 phases to land; boundary waits are COUNTED
// vmcnt(8) (never 0 mid-loop, T4) -- the younger burst stays in flight.
__global__ __launch_bounds__(512, 1) void gemm256_rope(const __hip_bfloat16* __restrict__ A,
                                                       const __hip_bfloat16* __restrict__ Bt,
                                                       __hip_bfloat16* __restrict__ C,
                                                       const float* __restrict__ tab) {
    __shared__ __align__(16) char lds[131072];
    const int tid = threadIdx.x;
    const int w = tid >> 6, lane = tid & 63;
    const int g = lane >> 4, fr = lane & 15;
    const int bn = blockIdx.x * 256, bm = blockIdx.y * 256;
    const int wm = (w >> 2) * 128, wn = (w & 3) * 64;

    const int srow = w*8 + (lane >> 3);
    const int scol = ((lane & 7) ^ (lane >> 3)) * 8;   // pre-swizzled source col
    const __hip_bfloat16* Asrc = A  + (size_t)(bm + srow)*DMODEL + scol;
    const __hip_bfloat16* Bsrc = Bt + (size_t)(bn + srow)*DMODEL + scol;

    f32x4 acc[8][4];
    #pragma unroll
    for (int i = 0; i < 8; ++i)
        #pragma unroll
        for (int j = 0; j < 4; ++j) acc[i][j] = (f32x4){0.f,0.f,0.f,0.f};

    auto stage = [&](int buf, int t) {
        char* base = lds + buf*65536;
        #pragma unroll
        for (int i = 0; i < 4; ++i)
            gldl(Asrc + (size_t)i*64*DMODEL + t*64, base + (i*64 + w*8)*128);
        #pragma unroll
        for (int i = 0; i < 4; ++i)
            gldl(Bsrc + (size_t)i*64*DMODEL + t*64, base + 32768 + (i*64 + w*8)*128);
    };
    auto rdA = [&](int buf, int mt, int ks) -> short8v {
        int row = wm + mt*16 + fr;
        return *(const short8v*)(lds + buf*65536 + row*128 + ((ks*64 + g*16) ^ ((fr&7)<<4)));
    };
    auto rdB = [&](int buf, int nt, int ks) -> short8v {
        int row = wn + nt*16 + fr;
        return *(const short8v*)(lds + buf*65536 + 32768 + row*128 + ((ks*64 + g*16) ^ ((fr&7)<<4)));
    };

    // one K-tile = 4 phases; stage_t >= 0: issue next+1 tile's loads in phase 4
    auto ktile = [&](int buf, int stage_t) {
        short8v a[8][2], b[4][2];
        // phase 1: 12 reads | MFMA m0-3 x n0-1
        #pragma unroll
        for (int mt = 0; mt < 4; ++mt)
            #pragma unroll
            for (int ks = 0; ks < 2; ++ks) a[mt][ks] = rdA(buf, mt, ks);
        #pragma unroll
        for (int nt = 0; nt < 2; ++nt)
            #pragma unroll
            for (int ks = 0; ks < 2; ++ks) b[nt][ks] = rdB(buf, nt, ks);
        __builtin_amdgcn_s_barrier();
        __builtin_amdgcn_s_setprio(1);
        #pragma unroll
        for (int mt = 0; mt < 4; ++mt)
            #pragma unroll
            for (int nt = 0; nt < 2; ++nt)
                #pragma unroll
                for (int ks = 0; ks < 2; ++ks)
                    acc[mt][nt] = __builtin_amdgcn_mfma_f32_16x16x32_bf16(a[mt][ks], b[nt][ks], acc[mt][nt], 0, 0, 0);
        __builtin_amdgcn_s_setprio(0);
        __builtin_amdgcn_s_barrier();
        // phase 2: 8 reads | MFMA m4-7 x n0-1
        #pragma unroll
        for (int mt = 4; mt < 8; ++mt)
            #pragma unroll
            for (int ks = 0; ks < 2; ++ks) a[mt][ks] = rdA(buf, mt, ks);
        __builtin_amdgcn_s_barrier();
        __builtin_amdgcn_s_setprio(1);
        #pragma unroll
        for (int mt = 4; mt < 8; ++mt)
            #pragma unroll
            for (int nt = 0; nt < 2; ++nt)
                #pragma unroll
                for (int ks = 0; ks < 2; ++ks)
                    acc[mt][nt] = __builtin_amdgcn_mfma_f32_16x16x32_bf16(a[mt][ks], b[nt][ks], acc[mt][nt], 0, 0, 0);
        __builtin_amdgcn_s_setprio(0);
        __builtin_amdgcn_s_barrier();
        // phase 3: 4 reads | MFMA m0-3 x n2-3  (last reads of this buffer)
        #pragma unroll
        for (int nt = 2; nt < 4; ++nt)
            #pragma unroll
            for (int ks = 0; ks < 2; ++ks) b[nt][ks] = rdB(buf, nt, ks);
        __builtin_amdgcn_s_barrier();
        __builtin_amdgcn_s_setprio(1);
        #pragma unroll
        for (int mt = 0; mt < 4; ++mt)
            #pragma unroll
            for (int nt = 2; nt < 4; ++nt)
                #pragma unroll
                for (int ks = 0; ks < 2; ++ks)
                    acc[mt][nt] = __builtin_amdgcn_mfma_f32_16x16x32_bf16(a[mt][ks], b[nt][ks], acc[mt][nt], 0, 0, 0);
        __builtin_amdgcn_s_setprio(0);
        __builtin_amdgcn_s_barrier();   // all waves done reading this buffer
        // phase 4: stage next+1 tile into this buffer | MFMA m4-7 x n2-3
        if (stage_t >= 0) stage(buf, stage_t);
        __builtin_amdgcn_s_setprio(1);
        #pragma unroll
        for (int mt = 4; mt < 8; ++mt)
            #pragma unroll
            for (int nt = 2; nt < 4; ++nt)
                #pragma unroll
                for (int ks = 0; ks < 2; ++ks)
                    acc[mt][nt] = __builtin_amdgcn_mfma_f32_16x16x32_bf16(a[mt][ks], b[nt][ks], acc[mt][nt], 0, 0, 0);
        __builtin_amdgcn_s_setprio(0);
    };

    stage(0, 0);
    stage(1, 1);
    asm volatile("s_waitcnt vmcnt(8)" ::: "memory");   // tile0 landed; tile1 in flight
    __builtin_amdgcn_s_barrier();

    #pragma unroll 1
    for (int j = 0; j < 8; ++j) {                      // 16 K-tiles, 2 per iter
        ktile(0, (j < 7) ? 2*j + 2 : -1);
        if (j < 7) asm volatile("s_waitcnt vmcnt(8)" ::: "memory");
        else       asm volatile("s_waitcnt vmcnt(0)" ::: "memory");
        __builtin_amdgcn_s_barrier();
        ktile(1, (j < 7) ? 2*j + 3 : -1);
        if (j < 7) {
            asm volatile("s_waitcnt vmcnt(8)" ::: "memory");
            __builtin_amdgcn_s_barrier();
        }
    }
    __syncthreads();

    // epilogue: rope in-register -> LDS (swizzled) -> coalesced uint4 stores
    const bool dorope = (bn < 2048);
    #pragma unroll
    for (int mt = 0; mt < 8; ++mt) {
        #pragma unroll
        for (int nt = 0; nt < 4; ++nt) {
            int colLoc = wn + nt*16 + fr;
            int d = colLoc & 63, dc = d & ~1;
            #pragma unroll
            for (int r = 0; r < 4; ++r) {
                int rloc = wm + mt*16 + g*4 + r;
                float v = acc[mt][nt][r];
                float pv = __shfl_xor(v, 1, 64);
                float o = v;
                if (dorope) {
                    int n = (bm + rloc) & (NTOK - 1);
                    float2 t2 = *(const float2*)&tab[(size_t)n*64 + dc];
                    o = v*t2.x + ((d & 1) ? pv*t2.y : -pv*t2.y);
                }
                *(__hip_bfloat16*)(lds + rloc*512 + ((colLoc*2) ^ ((rloc&15)<<4))) = __float2bfloat16(o);
            }
        }
    }
    __syncthreads();
    #pragma unroll
    for (int p = 0; p < 16; ++p) {
        int idx = p*512 + tid;
        int rloc = idx >> 5, c16 = idx & 31;
        uint4 v = *(const uint4*)(lds + rloc*512 + ((c16*16) ^ ((rloc&15)<<4)));
        *(uint4*)((char*)(C + (size_t)(bm + rloc)*QKVC + bn) + c16*16) = v;
    }
}

// ---------------- 128x128 bf16 MFMA GEMM (out-proj), round-6 structure -----
__global__ __launch_bounds__(256, 2) void gemm_f32out(const __hip_bfloat16* __restrict__ A,
                                                      const __hip_bfloat16* __restrict__ Bt,
                                                      float* __restrict__ C,
                                                      int M, int N, int K) {
    __shared__ __hip_bfloat16 As[128*32];
    __shared__ __hip_bfloat16 Bs[128*32];
    const int tid = threadIdx.x;
    const int wid = tid >> 6, lane = tid & 63;
    const int bm = blockIdx.y * 128, bn = blockIdx.x * 128;
    const int wm = (wid >> 1) * 64, wn = (wid & 1) * 64;

    f32x4 acc[4][4];
    #pragma unroll
    for (int i = 0; i < 4; ++i)
        #pragma unroll
        for (int j = 0; j < 4; ++j)
            acc[i][j] = (f32x4){0.f, 0.f, 0.f, 0.f};

    const int c0 = wid*64 + lane;
    const int c1 = 256 + c0;
    const int r0 = c0 >> 2, kg0 = (c0 & 3) << 3;
    const int r1 = c1 >> 2, kg1 = (c1 & 3) << 3;
    const __hip_bfloat16* A0 = A + (size_t)(bm + r0)*K + kg0;
    const __hip_bfloat16* A1 = A + (size_t)(bm + r1)*K + kg1;
    const __hip_bfloat16* B0 = Bt + (size_t)(bn + r0)*K + kg0;
    const __hip_bfloat16* B1 = Bt + (size_t)(bn + r1)*K + kg1;

    const int fr = lane & 15;
    const int fk = (lane >> 4) << 3;

    for (int k0 = 0; k0 < K; k0 += 32) {
        gldl(A0 + k0, (char*)(As + wid*512));
        gldl(A1 + k0, (char*)(As + 2048 + wid*512));
        gldl(B0 + k0, (char*)(Bs + wid*512));
        gldl(B1 + k0, (char*)(Bs + 2048 + wid*512));
        __syncthreads();

        short8v a[4], b[4];
        #pragma unroll
        for (int mt = 0; mt < 4; ++mt)
            a[mt] = *(const short8v*)&As[(wm + mt*16 + fr)*32 + fk];
        #pragma unroll
        for (int nt = 0; nt < 4; ++nt)
            b[nt] = *(const short8v*)&Bs[(wn + nt*16 + fr)*32 + fk];
        #pragma unroll
        for (int mt = 0; mt < 4; ++mt)
            #pragma unroll
            for (int nt = 0; nt < 4; ++nt)
                acc[mt][nt] = __builtin_amdgcn_mfma_f32_16x16x32_bf16(a[mt], b[nt], acc[mt][nt], 0, 0, 0);
        __syncthreads();
    }

    const int rsub = (lane >> 4) << 2;
    #pragma unroll
    for (int mt = 0; mt < 4; ++mt) {
        int rbase = bm + wm + mt*16 + rsub;
        #pragma unroll
        for (int nt = 0; nt < 4; ++nt) {
            int col = bn + wn + nt*16 + fr;
            #pragma unroll
            for (int r = 0; r < 4; ++r)
                C[(size_t)(rbase + r)*N + col] = acc[mt][nt][r];
        }
    }
}

// ---------------- MFMA flash attention (bf16 qkv) ---------------------------
__device__ __forceinline__ void stage_load(const __hip_bfloat16* __restrict__ qkv,
                                           const __hip_bfloat16* __restrict__ pmb,
                                           int h, int srow, int tt, int skey, int sdg,
                                           uint4 kv[2]) {
    int kg = tt*64 + skey;
    if (kg < PMEM) {
        kv[0] = *(const uint4*)(pmb + ((size_t)h*PMEM + kg)*DH + sdg);
        kv[1] = *(const uint4*)(pmb + ((size_t)(HEADS_ + h)*PMEM + kg)*DH + sdg);
    } else {
        int r = min(kg - PMEM, SEG_ - 1);   // clamp tail (masked anyway)
        const __hip_bfloat16* bp = qkv + (size_t)(srow + r)*QKVC + h*DH + sdg;
        kv[0] = *(const uint4*)(bp + 1024);
        kv[1] = *(const uint4*)(bp + 2048);
    }
}

__device__ __forceinline__ void stage_write(char* Kb, char* Vb,
                                            int skey, int sdg, const uint4 kv[2]) {
    *(uint4*)(Kb + ((skey*128 + sdg*2) ^ ((skey&7)<<4))) = kv[0];
    union { uint4 u; ushort s[8]; } vv; vv.u = kv[1];
    #pragma unroll
    for (int j = 0; j < 8; ++j) {
        int d = sdg + j;
        *(ushort*)(Vb + ((d*128 + skey*2) ^ ((d&7)<<4))) = vv.s[j];
    }
}

__global__ __launch_bounds__(512, 2) void attn_mfma(const __hip_bfloat16* __restrict__ qkv,
                                                    const __hip_bfloat16* __restrict__ pmb,
                                                    __hip_bfloat16* __restrict__ ao) {
    __shared__ __hip_bfloat16 KB[2][4096];
    __shared__ __hip_bfloat16 VB[2][4096];
    __shared__ __hip_bfloat16 PB[8][1024];

    const int s = blockIdx.x, h = blockIdx.y, rb = blockIdx.z;
    const int srow = (s >> 3)*NTOK + (s & 7)*SEG_;
    const int tid = threadIdx.x;
    const int w = tid >> 6, lane = tid & 63;
    const int g = lane >> 4, fr = lane & 15;
    const int rsub = g * 4;
    char* Pw = (char*)&PB[w][0];

    const int grp0 = 2*w + rb;
    const int grp1 = 30 - 2*w + rb;
    const int tmax = 7 + rb;

    short8v aq[2][2];
    #pragma unroll
    for (int mt = 0; mt < 2; ++mt) {
        int grp = mt ? grp1 : grp0;
        const __hip_bfloat16* qp = qkv + (size_t)(srow + grp*16 + fr)*QKVC + h*DH;
        #pragma unroll
        for (int ks = 0; ks < 2; ++ks)
            aq[mt][ks] = *(const short8v*)(qp + ks*32 + g*8);
    }

    f32x4 accO[2][4];
    float m_[2][4], l_[2][4];
    #pragma unroll
    for (int mt = 0; mt < 2; ++mt) {
        #pragma unroll
        for (int dt = 0; dt < 4; ++dt) accO[mt][dt] = (f32x4){0.f,0.f,0.f,0.f};
        #pragma unroll
        for (int r = 0; r < 4; ++r) { m_[mt][r] = -1e30f; l_[mt][r] = 0.f; }
    }

    const int skey = tid >> 3, sdg = (tid & 7) * 8;

    {
        uint4 kv[2];
        stage_load(qkv, pmb, h, srow, 0, skey, sdg, kv);
        stage_write((char*)&KB[0][0], (char*)&VB[0][0], skey, sdg, kv);
    }
    __syncthreads();

    for (int t = 0; t <= tmax; ++t) {
        const int bf = t & 1;
        uint4 kvn[2];
        if (t < tmax) stage_load(qkv, pmb, h, srow, t + 1, skey, sdg, kvn);

        char* Kb = (char*)&KB[bf][0];
        char* Vb = (char*)&VB[bf][0];

        short8v bk[4][2];
        #pragma unroll
        for (int nt = 0; nt < 4; ++nt)
            #pragma unroll
            for (int ks = 0; ks < 2; ++ks) {
                int row = nt*16 + fr;
                bk[nt][ks] = *(const short8v*)(Kb + ((row*128 + ks*64 + g*16) ^ ((row&7)<<4)));
            }

        #pragma unroll
        for (int mt = 0; mt < 2; ++mt) {
            const int qb = (mt ? grp1 : grp0) * 16;
            if (t > 0 && t*64 > qb + 31) continue;

            f32x4 sA[4];
            #pragma unroll
            for (int nt = 0; nt < 4; ++nt) sA[nt] = (f32x4){0.f,0.f,0.f,0.f};
            __builtin_amdgcn_s_setprio(1);
            #pragma unroll
            for (int ks = 0; ks < 2; ++ks)
                #pragma unroll
                for (int nt = 0; nt < 4; ++nt)
                    sA[nt] = __builtin_amdgcn_mfma_f32_16x16x32_bf16(aq[mt][ks], bk[nt][ks], sA[nt], 0, 0, 0);
            __builtin_amdgcn_s_setprio(0);

            if (!(t*64 + 63 <= qb + 16)) {
                #pragma unroll
                for (int nt = 0; nt < 4; ++nt) {
                    int kg2 = t*64 + nt*16 + fr;
                    #pragma unroll
                    for (int r = 0; r < 4; ++r) {
                        int irow = qb + rsub + r;
                        if (!((kg2 < PMEM) || (kg2 <= irow + PMEM))) sA[nt][r] = -1e30f;
                    }
                }
            }

            float mx[4], corr[4];
            #pragma unroll
            for (int r = 0; r < 4; ++r)
                mx[r] = fmaxf(fmaxf(sA[0][r], sA[1][r]), fmaxf(sA[2][r], sA[3][r]));
            #pragma unroll
            for (int r = 0; r < 4; ++r) {
                #pragma unroll
                for (int off = 1; off <= 8; off <<= 1)
                    mx[r] = fmaxf(mx[r], __shfl_xor(mx[r], off, 64));
                float mn = fmaxf(m_[mt][r], mx[r]);
                corr[r] = __expf((m_[mt][r] - mn)*0.125f);
                m_[mt][r] = mn;
            }
            #pragma unroll
            for (int nt = 0; nt < 4; ++nt)
                #pragma unroll
                for (int r = 0; r < 4; ++r)
                    sA[nt][r] = __expf((sA[nt][r] - m_[mt][r])*0.125f);
            #pragma unroll
            for (int r = 0; r < 4; ++r) {
                float lp = sA[0][r] + sA[1][r] + sA[2][r] + sA[3][r];
                l_[mt][r] = l_[mt][r]*corr[r] + lp;
            }
            #pragma unroll
            for (int dt = 0; dt < 4; ++dt)
                #pragma unroll
                for (int r = 0; r < 4; ++r)
                    accO[mt][dt][r] *= corr[r];

            #pragma unroll
            for (int nt = 0; nt < 4; ++nt)
                #pragma unroll
                for (int r = 0; r < 4; ++r) {
                    int row_l = rsub + r;
                    *(__hip_bfloat16*)(Pw + ((row_l*128 + (nt*16 + fr)*2) ^ ((row_l&7)<<4))) =
                        __float2bfloat16(sA[nt][r]);
                }

            __builtin_amdgcn_s_setprio(1);
            #pragma unroll
            for (int ks2 = 0; ks2 < 2; ++ks2) {
                short8v ap = *(const short8v*)(Pw + ((fr*128 + ks2*64 + g*16) ^ ((fr&7)<<4)));
                #pragma unroll
                for (int dt = 0; dt < 4; ++dt) {
                    int vrow = dt*16 + fr;
                    short8v bv = *(const short8v*)(Vb + ((vrow*128 + ks2*64 + g*16) ^ ((vrow&7)<<4)));
                    accO[mt][dt] = __builtin_amdgcn_mfma_f32_16x16x32_bf16(ap, bv, accO[mt][dt], 0, 0, 0);
                }
            }
            __builtin_amdgcn_s_setprio(0);
        }

        if (t < tmax) stage_write((char*)&KB[bf^1][0], (char*)&VB[bf^1][0], skey, sdg, kvn);
        __syncthreads();
    }

    #pragma unroll
    for (int mt = 0; mt < 2; ++mt) {
        const int grp = mt ? grp1 : grp0;
        float inv[4];
        #pragma unroll
        for (int r = 0; r < 4; ++r) {
            float lt = l_[mt][r];
            #pragma unroll
            for (int off = 1; off <= 8; off <<= 1) lt += __shfl_xor(lt, off, 64);
            inv[r] = 1.0f / lt;
        }
        #pragma unroll
        for (int dt = 0; dt < 4; ++dt)
            #pragma unroll
            for (int r = 0; r < 4; ++r) {
                int row_l = rsub + r;
                *(__hip_bfloat16*)(Pw + ((row_l*128 + (dt*16 + fr)*2) ^ ((row_l&7)<<4))) =
                    __float2bfloat16(accO[mt][dt][r] * inv[r]);
            }
        #pragma unroll
        for (int c = 0; c < 2; ++c) {
            int row_l = c*8 + (lane >> 3);
            size_t grow = (size_t)(srow + grp*16 + row_l);
            uint4 v = *(const uint4*)(Pw + ((row_l*128 + (lane&7)*16) ^ ((row_l&7)<<4)));
            *(uint4*)((char*)(ao + grow*DMODEL + h*DH) + (lane&7)*16) = v;
        }
    }
}

extern "C" void kernel_launch(void* const* d_in, const int* in_sizes, int n_in,
                              void* d_out, int out_size, void* d_ws, size_t ws_size,
                              hipStream_t stream) {
    const float* seq  = (const float*)d_in[0];
    const float* g    = (const float*)d_in[1];
    const float* wqkv = (const float*)d_in[2];
    const float* wout = (const float*)d_in[3];
    const float* pm   = (const float*)d_in[4];
    float* out = (float*)d_out;

    char* ws = (char*)d_ws;
    __hip_bfloat16* qkvb  = (__hip_bfloat16*)ws;                          // 48 MB
    __hip_bfloat16* xb    = (__hip_bfloat16*)(ws + 50331648);             // 16 MB (x, later ao)
    __hip_bfloat16* wqkvt = (__hip_bfloat16*)(ws + 50331648 + 16777216);  // 6 MB
    __hip_bfloat16* woutt = (__hip_bfloat16*)(ws + 50331648 + 16777216 + 6291456); // 2 MB
    float* tab            = (float*)(ws + 50331648 + 16777216 + 6291456 + 2097152); // 1 MB
    __hip_bfloat16* pmb   = (__hip_bfloat16*)(ws + 50331648 + 16777216 + 6291456 + 2097152 + 1048576); // 64 KB

    rope_table<<<(NTOK*32)/256, 256, 0, stream>>>(tab);
    pm_bf16<<<(2*HEADS_*PMEM*DH)/256, 256, 0, stream>>>(pm, pmb);
    transpose_bf16<<<dim3(QKVC/32, DMODEL/32), 256, 0, stream>>>(wqkv, wqkvt, DMODEL, QKVC);
    transpose_bf16<<<dim3(DMODEL/32, DMODEL/32), 256, 0, stream>>>(wout, woutt, DMODEL, DMODEL);
    rmsnorm_bf16<<<ROWS, 256, 0, stream>>>(seq, g, xb);
    gemm256_rope<<<dim3(QKVC/256, ROWS/256), 512, 0, stream>>>(xb, wqkvt, qkvb, tab);
    attn_mfma<<<dim3(16, 16, 2), 512, 0, stream>>>(qkvb, pmb, xb);
    gemm_f32out<<<dim3(DMODEL/128, ROWS/128), 256, 0, stream>>>(xb, woutt, out, ROWS, DMODEL, DMODEL);
}

// Round 10
// 204.097 us; speedup vs baseline: 1.1263x; 1.1263x over previous
//
#include <hip/hip_runtime.h>
#include <hip/hip_bf16.h>

typedef __attribute__((ext_vector_type(8))) short short8v;
typedef __attribute__((ext_vector_type(4))) float f32x4;

#define B_ 2
#define NTOK 4096
#define DMODEL 1024
#define HEADS_ 16
#define DH 64
#define SEG_ 512
#define PMEM 16
#define ROWS 8192      // B_*NTOK
#define QKVC 3072

// ---------------- RMSNorm -> bf16 ----------------
__global__ __launch_bounds__(256) void rmsnorm_bf16(const float* __restrict__ seq,
                                                    const float* __restrict__ g,
                                                    __hip_bfloat16* __restrict__ x) {
    int row = blockIdx.x;
    const float4* in = (const float4*)(seq + (size_t)row * DMODEL);
    int tid = threadIdx.x;
    float4 v = in[tid];
    float ss = v.x*v.x + v.y*v.y + v.z*v.z + v.w*v.w;
    #pragma unroll
    for (int off = 32; off >= 1; off >>= 1) ss += __shfl_xor(ss, off, 64);
    __shared__ float red[4];
    if ((tid & 63) == 0) red[tid >> 6] = ss;
    __syncthreads();
    float tot = red[0] + red[1] + red[2] + red[3];
    float scale = rsqrtf(tot * (1.0f/(float)DMODEL) + 1.1920929e-7f);
    float4 gv = ((const float4*)g)[tid];
    union { ushort4 u; __hip_bfloat16 h[4]; } pk;
    pk.h[0] = __float2bfloat16(v.x*scale*gv.x);
    pk.h[1] = __float2bfloat16(v.y*scale*gv.y);
    pk.h[2] = __float2bfloat16(v.z*scale*gv.z);
    pk.h[3] = __float2bfloat16(v.w*scale*gv.w);
    ((ushort4*)(x + (size_t)row * DMODEL))[tid] = pk.u;
}

// ---------------- transpose + convert: W[K,N] f32 -> Wt[N,K] bf16 ----------
__global__ __launch_bounds__(256) void transpose_bf16(const float* __restrict__ W,
                                                      __hip_bfloat16* __restrict__ Wt,
                                                      int K, int N) {
    __shared__ float t[32][33];
    int n0 = blockIdx.x * 32, k0 = blockIdx.y * 32;
    int c = threadIdx.x & 31, r = threadIdx.x >> 5;
    #pragma unroll
    for (int rr = 0; rr < 32; rr += 8)
        t[rr + r][c] = W[(size_t)(k0 + rr + r)*N + n0 + c];
    __syncthreads();
    #pragma unroll
    for (int rr = 0; rr < 32; rr += 8)
        Wt[(size_t)(n0 + rr + r)*K + k0 + c] = __float2bfloat16(t[c][rr + r]);
}

// ---------------- prep: RoPE cos/sin table + pm f32->bf16 -------------------
__global__ __launch_bounds__(256) void prep_kernel(float* __restrict__ tab,
                                                   const float* __restrict__ pm,
                                                   __hip_bfloat16* __restrict__ pmb) {
    int idx = blockIdx.x*256 + threadIdx.x;
    if (idx < NTOK*32) {
        int n = idx >> 5, p = idx & 31;
        float inv = powf(10000.f, -(float)p * (1.f/32.f));
        float a = (float)n * inv;
        float sn, cs;
        sincosf(a, &sn, &cs);
        tab[(size_t)n*64 + 2*p]     = cs;
        tab[(size_t)n*64 + 2*p + 1] = sn;
    } else {
        int j = idx - NTOK*32;      // 32768 pm elements
        pmb[j] = __float2bfloat16(pm[j]);
    }
}

__device__ __forceinline__ void gldl(const __hip_bfloat16* g, char* l) {
    __builtin_amdgcn_global_load_lds((const __attribute__((address_space(1))) void*)g,
                                     (__attribute__((address_space(3))) void*)l, 16, 0, 0);
}

// ---------------- 256x128 2-phase bf16 GEMM + fused RoPE (QKV) -------------
// Round-9 redesign: live set must fit VGPR budget (round-8 post-mortem:
// acc128+frags96 > 128 -> compiler remat'd ds_reads inside MFMA clusters).
// BM=256 BN=128 BK=64: acc 8x2 f32x4 = 64 VGPR, per-phase frags 48.
// Grid 32x24 = 768 = 3x256 exact dispatch rounds. LDS 96KB (2 x 48KB).
// Per K-tile 2 phases (m-half x full-n, 16 MFMA each); A-frags re-read per
// phase, B live across both. stage(t+2) issues in phase B after the barrier
// proving buffer drained; boundary waits are counted vmcnt(6) (T4).
__global__ __launch_bounds__(512, 1) void gemm_qkv(const __hip_bfloat16* __restrict__ A,
                                                   const __hip_bfloat16* __restrict__ Bt,
                                                   __hip_bfloat16* __restrict__ C,
                                                   const float* __restrict__ tab) {
    __shared__ __align__(16) char lds[98304];
    const int tid = threadIdx.x;
    const int w = tid >> 6, lane = tid & 63;
    const int g = lane >> 4, fr = lane & 15;
    const int bn = blockIdx.x * 128, bm = blockIdx.y * 256;
    const int wm = (w >> 2) * 128, wn = (w & 3) * 32;

    // staging: thread covers row tid>>3 (of 64 per issue), 16B chunk tid&7;
    // source col pre-swizzled so linear LDS holds the swizzled layout
    const int srow = tid >> 3;
    const int scol = ((tid & 7) ^ (srow & 7)) * 8;
    const __hip_bfloat16* Asrc = A  + (size_t)(bm + srow)*DMODEL + scol;
    const __hip_bfloat16* Bsrc = Bt + (size_t)(bn + srow)*DMODEL + scol;

    f32x4 acc[8][2];
    #pragma unroll
    for (int i = 0; i < 8; ++i) {
        acc[i][0] = (f32x4){0.f,0.f,0.f,0.f};
        acc[i][1] = (f32x4){0.f,0.f,0.f,0.f};
    }

    auto stage = [&](int buf, int t) {      // 6 gldl/thread: A 4, B 2
        char* base = lds + buf*49152;
        #pragma unroll
        for (int i = 0; i < 4; ++i)
            gldl(Asrc + (size_t)i*64*DMODEL + t*64, base + i*8192 + tid*16);
        #pragma unroll
        for (int i = 0; i < 2; ++i)
            gldl(Bsrc + (size_t)i*64*DMODEL + t*64, base + 32768 + i*8192 + tid*16);
    };
    auto rdA = [&](int buf, int mt, int ks) -> short8v {
        int row = wm + mt*16 + fr;
        return *(const short8v*)(lds + buf*49152 + row*128 + ((ks*64 + g*16) ^ ((fr&7)<<4)));
    };
    auto rdB = [&](int buf, int nt, int ks) -> short8v {
        int row = wn + nt*16 + fr;
        return *(const short8v*)(lds + buf*49152 + 32768 + row*128 + ((ks*64 + g*16) ^ ((fr&7)<<4)));
    };

    auto ktile = [&](int buf, int stage_t) {
        short8v a[4][2], b[2][2];
        // phase A: 12 reads | MFMA m0-3 x n0-1
        #pragma unroll
        for (int mt = 0; mt < 4; ++mt)
            #pragma unroll
            for (int ks = 0; ks < 2; ++ks) a[mt][ks] = rdA(buf, mt, ks);
        #pragma unroll
        for (int nt = 0; nt < 2; ++nt)
            #pragma unroll
            for (int ks = 0; ks < 2; ++ks) b[nt][ks] = rdB(buf, nt, ks);
        __builtin_amdgcn_s_barrier();
        __builtin_amdgcn_s_setprio(1);
        #pragma unroll
        for (int mt = 0; mt < 4; ++mt)
            #pragma unroll
            for (int nt = 0; nt < 2; ++nt)
                #pragma unroll
                for (int ks = 0; ks < 2; ++ks)
                    acc[mt][nt] = __builtin_amdgcn_mfma_f32_16x16x32_bf16(a[mt][ks], b[nt][ks], acc[mt][nt], 0, 0, 0);
        __builtin_amdgcn_s_setprio(0);
        __builtin_amdgcn_s_barrier();
        // phase B: 8 reads (m4-7); barrier proves buffer drained; stage; MFMA
        #pragma unroll
        for (int mt = 0; mt < 4; ++mt)
            #pragma unroll
            for (int ks = 0; ks < 2; ++ks) a[mt][ks] = rdA(buf, mt + 4, ks);
        __builtin_amdgcn_s_barrier();
        if (stage_t >= 0) stage(buf, stage_t);
        __builtin_amdgcn_s_setprio(1);
        #pragma unroll
        for (int mt = 0; mt < 4; ++mt)
            #pragma unroll
            for (int nt = 0; nt < 2; ++nt)
                #pragma unroll
                for (int ks = 0; ks < 2; ++ks)
                    acc[mt+4][nt] = __builtin_amdgcn_mfma_f32_16x16x32_bf16(a[mt][ks], b[nt][ks], acc[mt+4][nt], 0, 0, 0);
        __builtin_amdgcn_s_setprio(0);
    };

    stage(0, 0);
    stage(1, 1);
    asm volatile("s_waitcnt vmcnt(6)" ::: "memory");   // tile0 landed; tile1 in flight
    __builtin_amdgcn_s_barrier();

    #pragma unroll 1
    for (int j = 0; j < 8; ++j) {                      // 16 K-tiles, 2 per iter
        ktile(0, (j < 7) ? 2*j + 2 : -1);
        if (j < 7) asm volatile("s_waitcnt vmcnt(6)" ::: "memory");
        else       asm volatile("s_waitcnt vmcnt(0)" ::: "memory");
        __builtin_amdgcn_s_barrier();
        ktile(1, (j < 7) ? 2*j + 3 : -1);
        if (j < 7) {
            asm volatile("s_waitcnt vmcnt(6)" ::: "memory");
            __builtin_amdgcn_s_barrier();
        }
    }
    __syncthreads();

    // epilogue: rope in-register -> LDS (swizzled, 64KB) -> coalesced stores
    const bool dorope = (bn < 2048);
    #pragma unroll
    for (int mt = 0; mt < 8; ++mt) {
        #pragma unroll
        for (int nt = 0; nt < 2; ++nt) {
            int colLoc = wn + nt*16 + fr;
            int d = colLoc & 63, dc = d & ~1;
            #pragma unroll
            for (int r = 0; r < 4; ++r) {
                int rloc = wm + mt*16 + g*4 + r;
                float v = acc[mt][nt][r];
                float pv = __shfl_xor(v, 1, 64);
                float o = v;
                if (dorope) {
                    int n = (bm + rloc) & (NTOK - 1);
                    float2 t2 = *(const float2*)&tab[(size_t)n*64 + dc];
                    o = v*t2.x + ((d & 1) ? pv*t2.y : -pv*t2.y);
                }
                *(__hip_bfloat16*)(lds + rloc*256 + ((colLoc*2) ^ ((rloc&15)<<4))) = __float2bfloat16(o);
            }
        }
    }
    __syncthreads();
    #pragma unroll
    for (int p = 0; p < 8; ++p) {
        int idx = p*512 + tid;
        int rloc = idx >> 4, c16 = idx & 15;
        uint4 v = *(const uint4*)(lds + rloc*256 + ((c16*16) ^ ((rloc&15)<<4)));
        *(uint4*)((char*)(C + (size_t)(bm + rloc)*QKVC + bn) + c16*16) = v;
    }
}

// ---------------- 128x128 bf16 MFMA GEMM (out-proj) -------------------------
__global__ __launch_bounds__(256, 2) void gemm_f32out(const __hip_bfloat16* __restrict__ A,
                                                      const __hip_bfloat16* __restrict__ Bt,
                                                      float* __restrict__ C,
                                                      int M, int N, int K) {
    __shared__ __hip_bfloat16 As[128*32];
    __shared__ __hip_bfloat16 Bs[128*32];
    const int tid = threadIdx.x;
    const int wid = tid >> 6, lane = tid & 63;
    const int bm = blockIdx.y * 128, bn = blockIdx.x * 128;
    const int wm = (wid >> 1) * 64, wn = (wid & 1) * 64;

    f32x4 acc[4][4];
    #pragma unroll
    for (int i = 0; i < 4; ++i)
        #pragma unroll
        for (int j = 0; j < 4; ++j)
            acc[i][j] = (f32x4){0.f, 0.f, 0.f, 0.f};

    const int c0 = wid*64 + lane;
    const int c1 = 256 + c0;
    const int r0 = c0 >> 2, kg0 = (c0 & 3) << 3;
    const int r1 = c1 >> 2, kg1 = (c1 & 3) << 3;
    const __hip_bfloat16* A0 = A + (size_t)(bm + r0)*K + kg0;
    const __hip_bfloat16* A1 = A + (size_t)(bm + r1)*K + kg1;
    const __hip_bfloat16* B0 = Bt + (size_t)(bn + r0)*K + kg0;
    const __hip_bfloat16* B1 = Bt + (size_t)(bn + r1)*K + kg1;

    const int fr = lane & 15;
    const int fk = (lane >> 4) << 3;

    for (int k0 = 0; k0 < K; k0 += 32) {
        gldl(A0 + k0, (char*)(As + wid*512));
        gldl(A1 + k0, (char*)(As + 2048 + wid*512));
        gldl(B0 + k0, (char*)(Bs + wid*512));
        gldl(B1 + k0, (char*)(Bs + 2048 + wid*512));
        __syncthreads();

        short8v a[4], b[4];
        #pragma unroll
        for (int mt = 0; mt < 4; ++mt)
            a[mt] = *(const short8v*)&As[(wm + mt*16 + fr)*32 + fk];
        #pragma unroll
        for (int nt = 0; nt < 4; ++nt)
            b[nt] = *(const short8v*)&Bs[(wn + nt*16 + fr)*32 + fk];
        #pragma unroll
        for (int mt = 0; mt < 4; ++mt)
            #pragma unroll
            for (int nt = 0; nt < 4; ++nt)
                acc[mt][nt] = __builtin_amdgcn_mfma_f32_16x16x32_bf16(a[mt], b[nt], acc[mt][nt], 0, 0, 0);
        __syncthreads();
    }

    const int rsub = (lane >> 4) << 2;
    #pragma unroll
    for (int mt = 0; mt < 4; ++mt) {
        int rbase = bm + wm + mt*16 + rsub;
        #pragma unroll
        for (int nt = 0; nt < 4; ++nt) {
            int col = bn + wn + nt*16 + fr;
            #pragma unroll
            for (int r = 0; r < 4; ++r)
                C[(size_t)(rbase + r)*N + col] = acc[mt][nt][r];
        }
    }
}

// ---------------- MFMA flash attention (bf16 qkv) ---------------------------
__device__ __forceinline__ void stage_load(const __hip_bfloat16* __restrict__ qkv,
                                           const __hip_bfloat16* __restrict__ pmb,
                                           int h, int srow, int tt, int skey, int sdg,
                                           uint4 kv[2]) {
    int kg = tt*64 + skey;
    if (kg < PMEM) {
        kv[0] = *(const uint4*)(pmb + ((size_t)h*PMEM + kg)*DH + sdg);
        kv[1] = *(const uint4*)(pmb + ((size_t)(HEADS_ + h)*PMEM + kg)*DH + sdg);
    } else {
        int r = min(kg - PMEM, SEG_ - 1);   // clamp tail (masked anyway)
        const __hip_bfloat16* bp = qkv + (size_t)(srow + r)*QKVC + h*DH + sdg;
        kv[0] = *(const uint4*)(bp + 1024);
        kv[1] = *(const uint4*)(bp + 2048);
    }
}

__device__ __forceinline__ void stage_write(char* Kb, char* Vb,
                                            int skey, int sdg, const uint4 kv[2]) {
    *(uint4*)(Kb + ((skey*128 + sdg*2) ^ ((skey&7)<<4))) = kv[0];
    union { uint4 u; ushort s[8]; } vv; vv.u = kv[1];
    #pragma unroll
    for (int j = 0; j < 8; ++j) {
        int d = sdg + j;
        *(ushort*)(Vb + ((d*128 + skey*2) ^ ((d&7)<<4))) = vv.s[j];
    }
}

__global__ __launch_bounds__(512, 2) void attn_mfma(const __hip_bfloat16* __restrict__ qkv,
                                                    const __hip_bfloat16* __restrict__ pmb,
                                                    __hip_bfloat16* __restrict__ ao) {
    __shared__ __hip_bfloat16 KB[2][4096];
    __shared__ __hip_bfloat16 VB[2][4096];
    __shared__ __hip_bfloat16 PB[8][1024];

    const int s = blockIdx.x, h = blockIdx.y, rb = blockIdx.z;
    const int srow = (s >> 3)*NTOK + (s & 7)*SEG_;
    const int tid = threadIdx.x;
    const int w = tid >> 6, lane = tid & 63;
    const int g = lane >> 4, fr = lane & 15;
    const int rsub = g * 4;
    char* Pw = (char*)&PB[w][0];

    const int grp0 = 2*w + rb;
    const int grp1 = 30 - 2*w + rb;
    const int tmax = 7 + rb;

    short8v aq[2][2];
    #pragma unroll
    for (int mt = 0; mt < 2; ++mt) {
        int grp = mt ? grp1 : grp0;
        const __hip_bfloat16* qp = qkv + (size_t)(srow + grp*16 + fr)*QKVC + h*DH;
        #pragma unroll
        for (int ks = 0; ks < 2; ++ks)
            aq[mt][ks] = *(const short8v*)(qp + ks*32 + g*8);
    }

    f32x4 accO[2][4];
    float m_[2][4], l_[2][4];
    #pragma unroll
    for (int mt = 0; mt < 2; ++mt) {
        #pragma unroll
        for (int dt = 0; dt < 4; ++dt) accO[mt][dt] = (f32x4){0.f,0.f,0.f,0.f};
        #pragma unroll
        for (int r = 0; r < 4; ++r) { m_[mt][r] = -1e30f; l_[mt][r] = 0.f; }
    }

    const int skey = tid >> 3, sdg = (tid & 7) * 8;

    {
        uint4 kv[2];
        stage_load(qkv, pmb, h, srow, 0, skey, sdg, kv);
        stage_write((char*)&KB[0][0], (char*)&VB[0][0], skey, sdg, kv);
    }
    __syncthreads();

    for (int t = 0; t <= tmax; ++t) {
        const int bf = t & 1;
        uint4 kvn[2];
        if (t < tmax) stage_load(qkv, pmb, h, srow, t + 1, skey, sdg, kvn);

        char* Kb = (char*)&KB[bf][0];
        char* Vb = (char*)&VB[bf][0];

        short8v bk[4][2];
        #pragma unroll
        for (int nt = 0; nt < 4; ++nt)
            #pragma unroll
            for (int ks = 0; ks < 2; ++ks) {
                int row = nt*16 + fr;
                bk[nt][ks] = *(const short8v*)(Kb + ((row*128 + ks*64 + g*16) ^ ((row&7)<<4)));
            }

        #pragma unroll
        for (int mt = 0; mt < 2; ++mt) {
            const int qb = (mt ? grp1 : grp0) * 16;
            if (t > 0 && t*64 > qb + 31) continue;

            f32x4 sA[4];
            #pragma unroll
            for (int nt = 0; nt < 4; ++nt) sA[nt] = (f32x4){0.f,0.f,0.f,0.f};
            __builtin_amdgcn_s_setprio(1);
            #pragma unroll
            for (int ks = 0; ks < 2; ++ks)
                #pragma unroll
                for (int nt = 0; nt < 4; ++nt)
                    sA[nt] = __builtin_amdgcn_mfma_f32_16x16x32_bf16(aq[mt][ks], bk[nt][ks], sA[nt], 0, 0, 0);
            __builtin_amdgcn_s_setprio(0);

            if (!(t*64 + 63 <= qb + 16)) {
                #pragma unroll
                for (int nt = 0; nt < 4; ++nt) {
                    int kg2 = t*64 + nt*16 + fr;
                    #pragma unroll
                    for (int r = 0; r < 4; ++r) {
                        int irow = qb + rsub + r;
                        if (!((kg2 < PMEM) || (kg2 <= irow + PMEM))) sA[nt][r] = -1e30f;
                    }
                }
            }

            float mx[4], corr[4];
            #pragma unroll
            for (int r = 0; r < 4; ++r)
                mx[r] = fmaxf(fmaxf(sA[0][r], sA[1][r]), fmaxf(sA[2][r], sA[3][r]));
            #pragma unroll
            for (int r = 0; r < 4; ++r) {
                #pragma unroll
                for (int off = 1; off <= 8; off <<= 1)
                    mx[r] = fmaxf(mx[r], __shfl_xor(mx[r], off, 64));
                float mn = fmaxf(m_[mt][r], mx[r]);
                corr[r] = __expf((m_[mt][r] - mn)*0.125f);
                m_[mt][r] = mn;
            }
            #pragma unroll
            for (int nt = 0; nt < 4; ++nt)
                #pragma unroll
                for (int r = 0; r < 4; ++r)
                    sA[nt][r] = __expf((sA[nt][r] - m_[mt][r])*0.125f);
            #pragma unroll
            for (int r = 0; r < 4; ++r) {
                float lp = sA[0][r] + sA[1][r] + sA[2][r] + sA[3][r];
                l_[mt][r] = l_[mt][r]*corr[r] + lp;
            }
            #pragma unroll
            for (int dt = 0; dt < 4; ++dt)
                #pragma unroll
                for (int r = 0; r < 4; ++r)
                    accO[mt][dt][r] *= corr[r];

            #pragma unroll
            for (int nt = 0; nt < 4; ++nt)
                #pragma unroll
                for (int r = 0; r < 4; ++r) {
                    int row_l = rsub + r;
                    *(__hip_bfloat16*)(Pw + ((row_l*128 + (nt*16 + fr)*2) ^ ((row_l&7)<<4))) =
                        __float2bfloat16(sA[nt][r]);
                }

            __builtin_amdgcn_s_setprio(1);
            #pragma unroll
            for (int ks2 = 0; ks2 < 2; ++ks2) {
                short8v ap = *(const short8v*)(Pw + ((fr*128 + ks2*64 + g*16) ^ ((fr&7)<<4)));
                #pragma unroll
                for (int dt = 0; dt < 4; ++dt) {
                    int vrow = dt*16 + fr;
                    short8v bv = *(const short8v*)(Vb + ((vrow*128 + ks2*64 + g*16) ^ ((vrow&7)<<4)));
                    accO[mt][dt] = __builtin_amdgcn_mfma_f32_16x16x32_bf16(ap, bv, accO[mt][dt], 0, 0, 0);
                }
            }
            __builtin_amdgcn_s_setprio(0);
        }

        if (t < tmax) stage_write((char*)&KB[bf^1][0], (char*)&VB[bf^1][0], skey, sdg, kvn);
        __syncthreads();
    }

    #pragma unroll
    for (int mt = 0; mt < 2; ++mt) {
        const int grp = mt ? grp1 : grp0;
        float inv[4];
        #pragma unroll
        for (int r = 0; r < 4; ++r) {
            float lt = l_[mt][r];
            #pragma unroll
            for (int off = 1; off <= 8; off <<= 1) lt += __shfl_xor(lt, off, 64);
            inv[r] = 1.0f / lt;
        }
        #pragma unroll
        for (int dt = 0; dt < 4; ++dt)
            #pragma unroll
            for (int r = 0; r < 4; ++r) {
                int row_l = rsub + r;
                *(__hip_bfloat16*)(Pw + ((row_l*128 + (dt*16 + fr)*2) ^ ((row_l&7)<<4))) =
                    __float2bfloat16(accO[mt][dt][r] * inv[r]);
            }
        #pragma unroll
        for (int c = 0; c < 2; ++c) {
            int row_l = c*8 + (lane >> 3);
            size_t grow = (size_t)(srow + grp*16 + row_l);
            uint4 v = *(const uint4*)(Pw + ((row_l*128 + (lane&7)*16) ^ ((row_l&7)<<4)));
            *(uint4*)((char*)(ao + grow*DMODEL + h*DH) + (lane&7)*16) = v;
        }
    }
}

extern "C" void kernel_launch(void* const* d_in, const int* in_sizes, int n_in,
                              void* d_out, int out_size, void* d_ws, size_t ws_size,
                              hipStream_t stream) {
    const float* seq  = (const float*)d_in[0];
    const float* g    = (const float*)d_in[1];
    const float* wqkv = (const float*)d_in[2];
    const float* wout = (const float*)d_in[3];
    const float* pm   = (const float*)d_in[4];
    float* out = (float*)d_out;

    char* ws = (char*)d_ws;
    __hip_bfloat16* qkvb  = (__hip_bfloat16*)ws;                          // 48 MB
    __hip_bfloat16* xb    = (__hip_bfloat16*)(ws + 50331648);             // 16 MB (x, later ao)
    __hip_bfloat16* wqkvt = (__hip_bfloat16*)(ws + 50331648 + 16777216);  // 6 MB
    __hip_bfloat16* woutt = (__hip_bfloat16*)(ws + 50331648 + 16777216 + 6291456); // 2 MB
    float* tab            = (float*)(ws + 50331648 + 16777216 + 6291456 + 2097152); // 1 MB
    __hip_bfloat16* pmb   = (__hip_bfloat16*)(ws + 50331648 + 16777216 + 6291456 + 2097152 + 1048576); // 64 KB

    prep_kernel<<<(NTOK*32 + 2*HEADS_*PMEM*DH)/256, 256, 0, stream>>>(tab, pm, pmb);
    transpose_bf16<<<dim3(QKVC/32, DMODEL/32), 256, 0, stream>>>(wqkv, wqkvt, DMODEL, QKVC);
    transpose_bf16<<<dim3(DMODEL/32, DMODEL/32), 256, 0, stream>>>(wout, woutt, DMODEL, DMODEL);
    rmsnorm_bf16<<<ROWS, 256, 0, stream>>>(seq, g, xb);
    gemm_qkv<<<dim3(QKVC/128, ROWS/256), 512, 0, stream>>>(xb, wqkvt, qkvb, tab);
    attn_mfma<<<dim3(16, 16, 2), 512, 0, stream>>>(qkvb, pmb, xb);
    gemm_f32out<<<dim3(DMODEL/128, ROWS/128), 256, 0, stream>>>(xb, woutt, out, ROWS, DMODEL, DMODEL);
}

// Round 11
// 175.189 us; speedup vs baseline: 1.3121x; 1.1650x over previous
//
#include <hip/hip_runtime.h>
#include <hip/hip_bf16.h>

typedef __attribute__((ext_vector_type(8))) short short8v;
typedef __attribute__((ext_vector_type(4))) float f32x4;

#define B_ 2
#define NTOK 4096
#define DMODEL 1024
#define HEADS_ 16
#define DH 64
#define SEG_ 512
#define PMEM 16
#define ROWS 8192      // B_*NTOK
#define QKVC 3072

// ---------------- RMSNorm -> bf16 ----------------
__global__ __launch_bounds__(256) void rmsnorm_bf16(const float* __restrict__ seq,
                                                    const float* __restrict__ g,
                                                    __hip_bfloat16* __restrict__ x) {
    int row = blockIdx.x;
    const float4* in = (const float4*)(seq + (size_t)row * DMODEL);
    int tid = threadIdx.x;
    float4 v = in[tid];
    float ss = v.x*v.x + v.y*v.y + v.z*v.z + v.w*v.w;
    #pragma unroll
    for (int off = 32; off >= 1; off >>= 1) ss += __shfl_xor(ss, off, 64);
    __shared__ float red[4];
    if ((tid & 63) == 0) red[tid >> 6] = ss;
    __syncthreads();
    float tot = red[0] + red[1] + red[2] + red[3];
    float scale = rsqrtf(tot * (1.0f/(float)DMODEL) + 1.1920929e-7f);
    float4 gv = ((const float4*)g)[tid];
    union { ushort4 u; __hip_bfloat16 h[4]; } pk;
    pk.h[0] = __float2bfloat16(v.x*scale*gv.x);
    pk.h[1] = __float2bfloat16(v.y*scale*gv.y);
    pk.h[2] = __float2bfloat16(v.z*scale*gv.z);
    pk.h[3] = __float2bfloat16(v.w*scale*gv.w);
    ((ushort4*)(x + (size_t)row * DMODEL))[tid] = pk.u;
}

// ---------------- transpose + convert: W[K,N] f32 -> Wt[N,K] bf16 ----------
__global__ __launch_bounds__(256) void transpose_bf16(const float* __restrict__ W,
                                                      __hip_bfloat16* __restrict__ Wt,
                                                      int K, int N) {
    __shared__ float t[32][33];
    int n0 = blockIdx.x * 32, k0 = blockIdx.y * 32;
    int c = threadIdx.x & 31, r = threadIdx.x >> 5;
    #pragma unroll
    for (int rr = 0; rr < 32; rr += 8)
        t[rr + r][c] = W[(size_t)(k0 + rr + r)*N + n0 + c];
    __syncthreads();
    #pragma unroll
    for (int rr = 0; rr < 32; rr += 8)
        Wt[(size_t)(n0 + rr + r)*K + k0 + c] = __float2bfloat16(t[c][rr + r]);
}

// ---------------- prep: RoPE cos/sin table + pm f32->bf16 -------------------
__global__ __launch_bounds__(256) void prep_kernel(float* __restrict__ tab,
                                                   const float* __restrict__ pm,
                                                   __hip_bfloat16* __restrict__ pmb) {
    int idx = blockIdx.x*256 + threadIdx.x;
    if (idx < NTOK*32) {
        int n = idx >> 5, p = idx & 31;
        float inv = powf(10000.f, -(float)p * (1.f/32.f));
        float a = (float)n * inv;
        float sn, cs;
        sincosf(a, &sn, &cs);
        tab[(size_t)n*64 + 2*p]     = cs;
        tab[(size_t)n*64 + 2*p + 1] = sn;
    } else {
        int j = idx - NTOK*32;      // 32768 pm elements
        pmb[j] = __float2bfloat16(pm[j]);
    }
}

__device__ __forceinline__ void gldl(const __hip_bfloat16* g, char* l) {
    __builtin_amdgcn_global_load_lds((const __attribute__((address_space(1))) void*)g,
                                     (__attribute__((address_space(3))) void*)l, 16, 0, 0);
}
__device__ __forceinline__ void storeC(float* p, float v) { *p = v; }
__device__ __forceinline__ void storeC(__hip_bfloat16* p, float v) { *p = __float2bfloat16(v); }

// ---------------- 128x128 bf16 MFMA GEMM, BK=64 two-panel, XCD swizzle ------
// Proven round-5 structure (2-barrier, gld_lds direct, 2 blocks/CU) with:
//  - BK=64 as two 32-col panels (same 64B-row LDS banking; same lane*16B
//    staging mapping, HW-verified wave-uniform-base constraint) -> half the
//    barrier/drain events (16 K-steps, 32 MFMA/wave per barrier)
//  - XCD-aware block swizzle (grid % 8 == 0): same-XCD blocks contiguous in
//    tile space -> A-panel L2 reuse.
// ROPE: fused interleaved rotary on cols < 2048 (block-uniform boundary).
template<typename OutT, bool ROPE>
__global__ __launch_bounds__(256, 2) void gemm_t(const __hip_bfloat16* __restrict__ A,
                                                 const __hip_bfloat16* __restrict__ Bt,
                                                 OutT* __restrict__ C,
                                                 const float* __restrict__ tab,
                                                 int M, int N, int K) {
    __shared__ __hip_bfloat16 As[8192];   // panel ks: [128][32], 64B rows
    __shared__ __hip_bfloat16 Bs[8192];
    const int tid = threadIdx.x;
    const int wid = tid >> 6, lane = tid & 63;
    // XCD swizzle: HW round-robins consecutive blockIdx across the 8 XCDs;
    // group bid%8 into contiguous tile ranges so each XCD sees neighbors.
    const int q8 = gridDim.x >> 3;
    const int swz = (blockIdx.x & 7) * q8 + (blockIdx.x >> 3);
    const int nbx = N >> 7;
    const int bm = (swz / nbx) * 128, bn = (swz % nbx) * 128;
    const int wm = (wid >> 1) * 64, wn = (wid & 1) * 64;
    const int fr = lane & 15, g = lane >> 4;

    const __hip_bfloat16* Abase = A  + (size_t)bm * K;
    const __hip_bfloat16* Bbase = Bt + (size_t)bn * K;

    f32x4 acc[4][4];
    #pragma unroll
    for (int i = 0; i < 4; ++i)
        #pragma unroll
        for (int j = 0; j < 4; ++j)
            acc[i][j] = (f32x4){0.f, 0.f, 0.f, 0.f};

    const int srow_in = lane >> 2;          // 0..15 within a wave-issue
    const int scol8  = (lane & 3) * 8;      // 8-col chunk within panel

    for (int k0 = 0; k0 < K; k0 += 64) {
        // stage: per operand, wave wid covers rows 32*wid..32*wid+31, both
        // panels; each gldl writes 64 lanes x 16B linearly (base + lane*16B).
        #pragma unroll
        for (int m = 0; m < 4; ++m) {
            int p = m & 1, rg = (wid << 1) + (m >> 1);
            gldl(Abase + (size_t)(rg*16 + srow_in)*K + k0 + p*32 + scol8,
                 (char*)(As + p*4096 + rg*512 + lane*8));
        }
        #pragma unroll
        for (int m = 0; m < 4; ++m) {
            int p = m & 1, rg = (wid << 1) + (m >> 1);
            gldl(Bbase + (size_t)(rg*16 + srow_in)*K + k0 + p*32 + scol8,
                 (char*)(Bs + p*4096 + rg*512 + lane*8));
        }
        __syncthreads();

        short8v a[4][2], b[4][2];
        #pragma unroll
        for (int mt = 0; mt < 4; ++mt)
            #pragma unroll
            for (int ks = 0; ks < 2; ++ks)
                a[mt][ks] = *(const short8v*)&As[ks*4096 + (wm + mt*16 + fr)*32 + g*8];
        #pragma unroll
        for (int nt = 0; nt < 4; ++nt)
            #pragma unroll
            for (int ks = 0; ks < 2; ++ks)
                b[nt][ks] = *(const short8v*)&Bs[ks*4096 + (wn + nt*16 + fr)*32 + g*8];
        #pragma unroll
        for (int mt = 0; mt < 4; ++mt)
            #pragma unroll
            for (int nt = 0; nt < 4; ++nt)
                #pragma unroll
                for (int ks = 0; ks < 2; ++ks)
                    acc[mt][nt] = __builtin_amdgcn_mfma_f32_16x16x32_bf16(a[mt][ks], b[nt][ks], acc[mt][nt], 0, 0, 0);
        __syncthreads();
    }

    const int rsub = (lane >> 4) << 2;
    if (ROPE && bn < 2048) {
        // interleaved rotary: partner col value lives in lane^1
        #pragma unroll
        for (int mt = 0; mt < 4; ++mt) {
            int rbase = bm + wm + mt*16 + rsub;
            #pragma unroll
            for (int nt = 0; nt < 4; ++nt) {
                int col = bn + wn + nt*16 + fr;
                int d = col & 63;
                int dc = d & ~1;
                #pragma unroll
                for (int r = 0; r < 4; ++r) {
                    float v = acc[mt][nt][r];
                    float pv = __shfl_xor(v, 1, 64);
                    int n = (rbase + r) & (NTOK - 1);
                    const float* tb = tab + (size_t)n*64;
                    float cs = tb[dc], sn = tb[dc+1];
                    float o = v*cs + ((d & 1) ? pv*sn : -pv*sn);
                    storeC(&C[(size_t)(rbase + r)*N + col], (float)o);
                }
            }
        }
    } else {
        #pragma unroll
        for (int mt = 0; mt < 4; ++mt) {
            int rbase = bm + wm + mt*16 + rsub;
            #pragma unroll
            for (int nt = 0; nt < 4; ++nt) {
                int col = bn + wn + nt*16 + fr;
                #pragma unroll
                for (int r = 0; r < 4; ++r)
                    storeC(&C[(size_t)(rbase + r)*N + col], acc[mt][nt][r]);
            }
        }
    }
}

// ---------------- MFMA flash attention (bf16 qkv) ---------------------------
// grid (16 seg, 16 head, 2 rb), 512 threads = 8 waves. 32 groups of 16 q-rows;
// block rb owns groups with parity rb; wave w owns groups {2w+rb, 30-2w+rb}.
// KV tiles of 64 keys (tile0 = 16 pmem + 48 seg keys), double-buffered LDS.
// K [key][d], V transposed [d][key], P per-wave [16][64]; XOR swizzle (row&7)<<4.
// Score scale 1/8 folded into exp args. l kept per-lane, reduced in epilogue.
// __launch_bounds__(512,2): (512,4) caps VGPR at 64 -> 0.5 GB scratch spills.
__device__ __forceinline__ void stage_load(const __hip_bfloat16* __restrict__ qkv,
                                           const __hip_bfloat16* __restrict__ pmb,
                                           int h, int srow, int tt, int skey, int sdg,
                                           uint4 kv[2]) {
    int kg = tt*64 + skey;
    if (kg < PMEM) {
        kv[0] = *(const uint4*)(pmb + ((size_t)h*PMEM + kg)*DH + sdg);
        kv[1] = *(const uint4*)(pmb + ((size_t)(HEADS_ + h)*PMEM + kg)*DH + sdg);
    } else {
        int r = min(kg - PMEM, SEG_ - 1);   // clamp tail (masked anyway)
        const __hip_bfloat16* bp = qkv + (size_t)(srow + r)*QKVC + h*DH + sdg;
        kv[0] = *(const uint4*)(bp + 1024);
        kv[1] = *(const uint4*)(bp + 2048);
    }
}

__device__ __forceinline__ void stage_write(char* Kb, char* Vb,
                                            int skey, int sdg, const uint4 kv[2]) {
    *(uint4*)(Kb + ((skey*128 + sdg*2) ^ ((skey&7)<<4))) = kv[0];
    union { uint4 u; ushort s[8]; } vv; vv.u = kv[1];
    #pragma unroll
    for (int j = 0; j < 8; ++j) {
        int d = sdg + j;
        *(ushort*)(Vb + ((d*128 + skey*2) ^ ((d&7)<<4))) = vv.s[j];
    }
}

__global__ __launch_bounds__(512, 2) void attn_mfma(const __hip_bfloat16* __restrict__ qkv,
                                                    const __hip_bfloat16* __restrict__ pmb,
                                                    __hip_bfloat16* __restrict__ ao) {
    __shared__ __hip_bfloat16 KB[2][4096];
    __shared__ __hip_bfloat16 VB[2][4096];
    __shared__ __hip_bfloat16 PB[8][1024];

    const int s = blockIdx.x, h = blockIdx.y, rb = blockIdx.z;
    const int srow = (s >> 3)*NTOK + (s & 7)*SEG_;
    const int tid = threadIdx.x;
    const int w = tid >> 6, lane = tid & 63;
    const int g = lane >> 4, fr = lane & 15;
    const int rsub = g * 4;
    char* Pw = (char*)&PB[w][0];

    const int grp0 = 2*w + rb;
    const int grp1 = 30 - 2*w + rb;
    const int tmax = 7 + rb;

    short8v aq[2][2];
    #pragma unroll
    for (int mt = 0; mt < 2; ++mt) {
        int grp = mt ? grp1 : grp0;
        const __hip_bfloat16* qp = qkv + (size_t)(srow + grp*16 + fr)*QKVC + h*DH;
        #pragma unroll
        for (int ks = 0; ks < 2; ++ks)
            aq[mt][ks] = *(const short8v*)(qp + ks*32 + g*8);
    }

    f32x4 accO[2][4];
    float m_[2][4], l_[2][4];
    #pragma unroll
    for (int mt = 0; mt < 2; ++mt) {
        #pragma unroll
        for (int dt = 0; dt < 4; ++dt) accO[mt][dt] = (f32x4){0.f,0.f,0.f,0.f};
        #pragma unroll
        for (int r = 0; r < 4; ++r) { m_[mt][r] = -1e30f; l_[mt][r] = 0.f; }
    }

    const int skey = tid >> 3, sdg = (tid & 7) * 8;

    {
        uint4 kv[2];
        stage_load(qkv, pmb, h, srow, 0, skey, sdg, kv);
        stage_write((char*)&KB[0][0], (char*)&VB[0][0], skey, sdg, kv);
    }
    __syncthreads();

    for (int t = 0; t <= tmax; ++t) {
        const int bf = t & 1;
        uint4 kvn[2];
        if (t < tmax) stage_load(qkv, pmb, h, srow, t + 1, skey, sdg, kvn);

        char* Kb = (char*)&KB[bf][0];
        char* Vb = (char*)&VB[bf][0];

        short8v bk[4][2];
        #pragma unroll
        for (int nt = 0; nt < 4; ++nt)
            #pragma unroll
            for (int ks = 0; ks < 2; ++ks) {
                int row = nt*16 + fr;
                bk[nt][ks] = *(const short8v*)(Kb + ((row*128 + ks*64 + g*16) ^ ((row&7)<<4)));
            }

        #pragma unroll
        for (int mt = 0; mt < 2; ++mt) {
            const int qb = (mt ? grp1 : grp0) * 16;
            if (t > 0 && t*64 > qb + 31) continue;

            f32x4 sA[4];
            #pragma unroll
            for (int nt = 0; nt < 4; ++nt) sA[nt] = (f32x4){0.f,0.f,0.f,0.f};
            __builtin_amdgcn_s_setprio(1);
            #pragma unroll
            for (int ks = 0; ks < 2; ++ks)
                #pragma unroll
                for (int nt = 0; nt < 4; ++nt)
                    sA[nt] = __builtin_amdgcn_mfma_f32_16x16x32_bf16(aq[mt][ks], bk[nt][ks], sA[nt], 0, 0, 0);
            __builtin_amdgcn_s_setprio(0);

            if (!(t*64 + 63 <= qb + 16)) {
                #pragma unroll
                for (int nt = 0; nt < 4; ++nt) {
                    int kg2 = t*64 + nt*16 + fr;
                    #pragma unroll
                    for (int r = 0; r < 4; ++r) {
                        int irow = qb + rsub + r;
                        if (!((kg2 < PMEM) || (kg2 <= irow + PMEM))) sA[nt][r] = -1e30f;
                    }
                }
            }

            float mx[4], corr[4];
            #pragma unroll
            for (int r = 0; r < 4; ++r)
                mx[r] = fmaxf(fmaxf(sA[0][r], sA[1][r]), fmaxf(sA[2][r], sA[3][r]));
            #pragma unroll
            for (int r = 0; r < 4; ++r) {
                #pragma unroll
                for (int off = 1; off <= 8; off <<= 1)
                    mx[r] = fmaxf(mx[r], __shfl_xor(mx[r], off, 64));
                float mn = fmaxf(m_[mt][r], mx[r]);
                corr[r] = __expf((m_[mt][r] - mn)*0.125f);
                m_[mt][r] = mn;
            }
            #pragma unroll
            for (int nt = 0; nt < 4; ++nt)
                #pragma unroll
                for (int r = 0; r < 4; ++r)
                    sA[nt][r] = __expf((sA[nt][r] - m_[mt][r])*0.125f);
            #pragma unroll
            for (int r = 0; r < 4; ++r) {
                float lp = sA[0][r] + sA[1][r] + sA[2][r] + sA[3][r];
                l_[mt][r] = l_[mt][r]*corr[r] + lp;
            }
            #pragma unroll
            for (int dt = 0; dt < 4; ++dt)
                #pragma unroll
                for (int r = 0; r < 4; ++r)
                    accO[mt][dt][r] *= corr[r];

            #pragma unroll
            for (int nt = 0; nt < 4; ++nt)
                #pragma unroll
                for (int r = 0; r < 4; ++r) {
                    int row_l = rsub + r;
                    *(__hip_bfloat16*)(Pw + ((row_l*128 + (nt*16 + fr)*2) ^ ((row_l&7)<<4))) =
                        __float2bfloat16(sA[nt][r]);
                }

            __builtin_amdgcn_s_setprio(1);
            #pragma unroll
            for (int ks2 = 0; ks2 < 2; ++ks2) {
                short8v ap = *(const short8v*)(Pw + ((fr*128 + ks2*64 + g*16) ^ ((fr&7)<<4)));
                #pragma unroll
                for (int dt = 0; dt < 4; ++dt) {
                    int vrow = dt*16 + fr;
                    short8v bv = *(const short8v*)(Vb + ((vrow*128 + ks2*64 + g*16) ^ ((vrow&7)<<4)));
                    accO[mt][dt] = __builtin_amdgcn_mfma_f32_16x16x32_bf16(ap, bv, accO[mt][dt], 0, 0, 0);
                }
            }
            __builtin_amdgcn_s_setprio(0);
        }

        if (t < tmax) stage_write((char*)&KB[bf^1][0], (char*)&VB[bf^1][0], skey, sdg, kvn);
        __syncthreads();
    }

    #pragma unroll
    for (int mt = 0; mt < 2; ++mt) {
        const int grp = mt ? grp1 : grp0;
        float inv[4];
        #pragma unroll
        for (int r = 0; r < 4; ++r) {
            float lt = l_[mt][r];
            #pragma unroll
            for (int off = 1; off <= 8; off <<= 1) lt += __shfl_xor(lt, off, 64);
            inv[r] = 1.0f / lt;
        }
        #pragma unroll
        for (int dt = 0; dt < 4; ++dt)
            #pragma unroll
            for (int r = 0; r < 4; ++r) {
                int row_l = rsub + r;
                *(__hip_bfloat16*)(Pw + ((row_l*128 + (dt*16 + fr)*2) ^ ((row_l&7)<<4))) =
                    __float2bfloat16(accO[mt][dt][r] * inv[r]);
            }
        #pragma unroll
        for (int c = 0; c < 2; ++c) {
            int row_l = c*8 + (lane >> 3);
            size_t grow = (size_t)(srow + grp*16 + row_l);
            uint4 v = *(const uint4*)(Pw + ((row_l*128 + (lane&7)*16) ^ ((row_l&7)<<4)));
            *(uint4*)((char*)(ao + grow*DMODEL + h*DH) + (lane&7)*16) = v;
        }
    }
}

extern "C" void kernel_launch(void* const* d_in, const int* in_sizes, int n_in,
                              void* d_out, int out_size, void* d_ws, size_t ws_size,
                              hipStream_t stream) {
    const float* seq  = (const float*)d_in[0];
    const float* g    = (const float*)d_in[1];
    const float* wqkv = (const float*)d_in[2];
    const float* wout = (const float*)d_in[3];
    const float* pm   = (const float*)d_in[4];
    float* out = (float*)d_out;

    char* ws = (char*)d_ws;
    __hip_bfloat16* qkvb  = (__hip_bfloat16*)ws;                          // 48 MB
    __hip_bfloat16* xb    = (__hip_bfloat16*)(ws + 50331648);             // 16 MB (x, later ao)
    __hip_bfloat16* wqkvt = (__hip_bfloat16*)(ws + 50331648 + 16777216);  // 6 MB
    __hip_bfloat16* woutt = (__hip_bfloat16*)(ws + 50331648 + 16777216 + 6291456); // 2 MB
    float* tab            = (float*)(ws + 50331648 + 16777216 + 6291456 + 2097152); // 1 MB
    __hip_bfloat16* pmb   = (__hip_bfloat16*)(ws + 50331648 + 16777216 + 6291456 + 2097152 + 1048576); // 64 KB

    prep_kernel<<<(NTOK*32 + 2*HEADS_*PMEM*DH)/256, 256, 0, stream>>>(tab, pm, pmb);
    transpose_bf16<<<dim3(QKVC/32, DMODEL/32), 256, 0, stream>>>(wqkv, wqkvt, DMODEL, QKVC);
    transpose_bf16<<<dim3(DMODEL/32, DMODEL/32), 256, 0, stream>>>(wout, woutt, DMODEL, DMODEL);
    rmsnorm_bf16<<<ROWS, 256, 0, stream>>>(seq, g, xb);
    gemm_t<__hip_bfloat16, true><<<(QKVC/128)*(ROWS/128), 256, 0, stream>>>(xb, wqkvt, qkvb, tab, ROWS, QKVC, DMODEL);
    attn_mfma<<<dim3(16, 16, 2), 512, 0, stream>>>(qkvb, pmb, xb);
    gemm_t<float, false><<<(DMODEL/128)*(ROWS/128), 256, 0, stream>>>(xb, woutt, out, nullptr, ROWS, DMODEL, DMODEL);
}